// Round 14
// baseline (30.766 us; speedup 1.0000x reference)
//
#include <hip/hip_runtime.h>

// Box filter 1024x1024 constant kernel, reflect pad (pl=pt=511, pr=pb=512).
// out = KC * H(V(x)) with V-first (linearity). 2-dispatch pipeline:
//  K1 scanx (round-11 verbatim): per (ch, 32-col slab) block (192 blocks):
//     read x slab, form 4-row band sums in LDS, per-column shuffle scan ->
//     BP4[ch][257][1024], BP4[k]=P[4k], BP4[256]=P[1024].
//  K2 vslideh: per (ch, 4-row band): vertical sliding recurrence on x gives
//     4 U rows in registers; rows H-transformed IN PAIRS (two interleaved
//     block scans -> 1 sync/row, 2x shfl-chain ILP), *KC -> out.
//    U[o] = U[o-1] + x[o+512] - x[512-o]   (1 <= o <= 510)
//    U[511] = P[1024]
//    U[o] = U[o-1] - x[o-512] + x[1534-o]  (513 <= o <= 1023)

static constexpr float KC = 2.5652997311834374e-21f;
#define IMG (1024 * 1024)

__device__ __forceinline__ float hwindow(const float* S, int o) {
    float r = 0.f;
    if (o <= 510) r += S[512 - o] - S[1];                 // left mirror
    const int b0 = o > 511 ? o - 511 : 0;                 // main
    const int b1 = o + 513 < 1024 ? o + 513 : 1024;
    r += S[b1] - S[b0];
    if (o >= 512) r += S[1023] - S[1534 - o];             // right mirror
    return r;
}

// Emit TWO rows: interleaved block scans (independent shfl chains), shared
// syncs (2 per pair). Safe to call back-to-back: next pair's wtot writes
// occur after this pair's second sync in every thread's program order, and
// all wtot/S reads precede it.
__device__ __forceinline__ void hrow_emit2(float4 u0, float4 u1,
                                           float* S0, float* S1,
                                           float* wt0, float* wt1,
                                           float* orow0, float* orow1, int t) {
    const float a0 = u0.x, a1 = a0 + u0.y, a2 = a1 + u0.z, a3 = a2 + u0.w;
    const float b0 = u1.x, b1 = b0 + u1.y, b2 = b1 + u1.z, b3 = b2 + u1.w;
    const int lane = t & 63, wave = t >> 6;
    float incA = a3, incB = b3;
    #pragma unroll
    for (int off = 1; off < 64; off <<= 1) {
        float nA = __shfl_up(incA, off);
        float nB = __shfl_up(incB, off);
        if (lane >= off) { incA += nA; incB += nB; }
    }
    if (lane == 63) { wt0[wave] = incA; wt1[wave] = incB; }
    __syncthreads();
    float woffA = 0.f, woffB = 0.f;
    for (int w = 0; w < wave; ++w) { woffA += wt0[w]; woffB += wt1[w]; }
    const float exA = woffA + incA - a3;
    const float exB = woffB + incB - b3;
    S0[4 * t + 0] = exA;      S1[4 * t + 0] = exB;
    S0[4 * t + 1] = exA + a0; S1[4 * t + 1] = exB + b0;
    S0[4 * t + 2] = exA + a1; S1[4 * t + 2] = exB + b1;
    S0[4 * t + 3] = exA + a2; S1[4 * t + 3] = exB + b2;
    if (t == 255) { S0[1024] = exA + a3; S1[1024] = exB + b3; }
    __syncthreads();
    const int ox = 4 * t;
    float4 o0, o1;
    o0.x = KC * hwindow(S0, ox + 0);
    o0.y = KC * hwindow(S0, ox + 1);
    o0.z = KC * hwindow(S0, ox + 2);
    o0.w = KC * hwindow(S0, ox + 3);
    o1.x = KC * hwindow(S1, ox + 0);
    o1.y = KC * hwindow(S1, ox + 1);
    o1.z = KC * hwindow(S1, ox + 2);
    o1.w = KC * hwindow(S1, ox + 3);
    reinterpret_cast<float4*>(orow0)[t] = o0;
    reinterpret_cast<float4*>(orow1)[t] = o1;
}

// ---- K1: band sums from x + per-column scan -> BP4 (round-11 verbatim) ----
// grid 192 = 6ch x 32 colslabs(32 cols), 256 threads
__global__ __launch_bounds__(256) void scanx_kernel(const float* __restrict__ x,
                                                    float* __restrict__ BP) {
    __shared__ float B[257][33];
    const int t = threadIdx.x;
    const int ch = blockIdx.x >> 5, cg = blockIdx.x & 31;
    const int col0 = cg * 32;
    const int c = t & 31, g = t >> 5;          // 8 row-groups of 32 lanes
    const float* xc = x + (size_t)ch * IMG + col0 + c;

    // 4-row band sums: thread (c,g) owns bands g, g+8, ..., g+248
    #pragma unroll 4
    for (int i = 0; i < 32; ++i) {
        const int band = g + 8 * i;
        const float* p = xc + (size_t)band * 4 * 1024;
        B[band][c] = (p[0] + p[1024]) + (p[2048] + p[3072]);
    }
    __syncthreads();

    // per-column scan over 256 bands (proven 4-segment body)
    const int lane = t & 63, wv = t >> 6;
    #pragma unroll
    for (int i = 0; i < 8; ++i) {
        const int cc = wv * 8 + i;
        float v0 = B[lane][cc], v1 = B[lane + 64][cc],
              v2 = B[lane + 128][cc], v3 = B[lane + 192][cc];
        float i0 = v0, i1 = v1, i2 = v2, i3 = v3;
        #pragma unroll
        for (int off = 1; off < 64; off <<= 1) {
            float n0 = __shfl_up(i0, off), n1 = __shfl_up(i1, off);
            float n2 = __shfl_up(i2, off), n3 = __shfl_up(i3, off);
            if (lane >= off) { i0 += n0; i1 += n1; i2 += n2; i3 += n3; }
        }
        const float t0 = __shfl(i0, 63), t1 = __shfl(i1, 63), t2 = __shfl(i2, 63);
        B[lane][cc]       = i0 - v0;
        B[lane + 64][cc]  = t0 + i1 - v1;
        B[lane + 128][cc] = t0 + t1 + i2 - v2;
        B[lane + 192][cc] = t0 + t1 + t2 + i3 - v3;
        if (lane == 63) B[256][cc] = t0 + t1 + t2 + i3;   // P[1024]
    }
    __syncthreads();

    // coalesced write-out of all 257 rows
    float* Bp = BP + (size_t)ch * 257 * 1024 + col0;
    #pragma unroll
    for (int i = 0; i < 33; ++i) {
        const int idx = i * 256 + t;
        if (idx < 257 * 32) {
            const int k = idx >> 5, cw = idx & 31;
            Bp[(size_t)k * 1024 + cw] = B[k][cw];
        }
    }
}

// ---- K2: vertical slide + paired in-block horizontal. grid 1536 -----------
__global__ __launch_bounds__(256) void vslideh_kernel(const float* __restrict__ x,
                                                      const float* __restrict__ BP,
                                                      float* __restrict__ out) {
    __shared__ float S[2][1025];
    __shared__ float wtot[2][4];
    const int t = threadIdx.x;
    const int ch = blockIdx.x >> 8, band = blockIdx.x & 255;
    const int O = band * 4;
    const float* xc = x + (size_t)ch * IMG;
    const float* Bc = BP + (size_t)ch * 257 * 1024;
    float* oc = out + (size_t)ch * IMG;

    #define LD4(base, row) (reinterpret_cast<const float4*>((base) + (size_t)(row) * 1024)[t])

    float4 u0, u1, u2, u3;
    if (band < 128) {
        // u0 = U[O] = P[512-O] - P[1] + P[O+513]
        const float4 bA = LD4(Bc, (512 - O) >> 2);
        const float4 x0 = LD4(xc, 0);
        const float4 bB = LD4(Bc, (512 + O) >> 2);
        const float4 xb = LD4(xc, O + 512);
        u0.x = bA.x - x0.x + bB.x + xb.x;
        u0.y = bA.y - x0.y + bB.y + xb.y;
        u0.z = bA.z - x0.z + bB.z + xb.z;
        u0.w = bA.w - x0.w + bB.w + xb.w;
        {
            const float4 a = LD4(xc, O + 513), s = LD4(xc, 511 - O);
            u1.x = u0.x + a.x - s.x; u1.y = u0.y + a.y - s.y;
            u1.z = u0.z + a.z - s.z; u1.w = u0.w + a.w - s.w;
        }
        {
            const float4 a = LD4(xc, O + 514), s = LD4(xc, 510 - O);
            u2.x = u1.x + a.x - s.x; u2.y = u1.y + a.y - s.y;
            u2.z = u1.z + a.z - s.z; u2.w = u1.w + a.w - s.w;
        }
        if (band == 127) {
            u3 = LD4(Bc, 256);                       // U[511] = P[1024]
        } else {
            const float4 a = LD4(xc, O + 515), s = LD4(xc, 509 - O);
            u3.x = u2.x + a.x - s.x; u3.y = u2.y + a.y - s.y;
            u3.z = u2.z + a.z - s.z; u3.w = u2.w + a.w - s.w;
        }
    } else {
        // init U[O-1] = P[1024] - P[O-512] + P[1023] - P[1535-O]
        const float4 bt = LD4(Bc, 256);
        const float4 bA = LD4(Bc, (O - 512) >> 2);
        const float4 xm = LD4(xc, 1023);
        const float4 bB = LD4(Bc, (1536 - O) >> 2);
        const float4 xf = LD4(xc, 1535 - O);
        float4 acc;
        acc.x = bt.x - bA.x + (bt.x - xm.x) - (bB.x - xf.x);
        acc.y = bt.y - bA.y + (bt.y - xm.y) - (bB.y - xf.y);
        acc.z = bt.z - bA.z + (bt.z - xm.z) - (bB.z - xf.z);
        acc.w = bt.w - bA.w + (bt.w - xm.w) - (bB.w - xf.w);
        {
            const float4 a = LD4(xc, 1534 - O), s = LD4(xc, O - 512);
            u0.x = acc.x + a.x - s.x; u0.y = acc.y + a.y - s.y;
            u0.z = acc.z + a.z - s.z; u0.w = acc.w + a.w - s.w;
        }
        {
            const float4 a = LD4(xc, 1533 - O), s = LD4(xc, O - 511);
            u1.x = u0.x + a.x - s.x; u1.y = u0.y + a.y - s.y;
            u1.z = u0.z + a.z - s.z; u1.w = u0.w + a.w - s.w;
        }
        {
            const float4 a = LD4(xc, 1532 - O), s = LD4(xc, O - 510);
            u2.x = u1.x + a.x - s.x; u2.y = u1.y + a.y - s.y;
            u2.z = u1.z + a.z - s.z; u2.w = u1.w + a.w - s.w;
        }
        {
            const float4 a = LD4(xc, 1531 - O), s = LD4(xc, O - 509);
            u3.x = u2.x + a.x - s.x; u3.y = u2.y + a.y - s.y;
            u3.z = u2.z + a.z - s.z; u3.w = u2.w + a.w - s.w;
        }
    }
    #undef LD4

    hrow_emit2(u0, u1, S[0], S[1], wtot[0], wtot[1],
               oc + (size_t)O * 1024, oc + (size_t)(O + 1) * 1024, t);
    hrow_emit2(u2, u3, S[0], S[1], wtot[0], wtot[1],
               oc + (size_t)(O + 2) * 1024, oc + (size_t)(O + 3) * 1024, t);
}

extern "C" void kernel_launch(void* const* d_in, const int* in_sizes, int n_in,
                              void* d_out, int out_size, void* d_ws, size_t ws_size,
                              hipStream_t stream) {
    const float* x = (const float*)d_in[2];
    float* out = (float*)d_out;
    float* BP = (float*)d_ws;                        // 6*257*1024 floats
    scanx_kernel<<<192, 256, 0, stream>>>(x, BP);
    vslideh_kernel<<<1536, 256, 0, stream>>>(x, BP, out);
}